// Round 1
// baseline (254013.696 us; speedup 1.0000x reference)
//
#include <hip/hip_runtime.h>
#include <math.h>

#define T_STEPS 8192
#define HID     2048
#define IN_SZ   256
#define OUT_SZ  128
#define NBLK    256            // scan workgroups (1 per CU)
#define RPB     8              // rows per workgroup = HID/NBLK
#define NTAGS   (NBLK * 4)     // one tag per wave

typedef unsigned long long u64;

// ---------------------------------------------------------------------------
// ws layout: [0, 3*HID) floats = r ring buffer (depth 3); then NTAGS ints.
// ---------------------------------------------------------------------------

__global__ void k_init(const float* __restrict__ rate, float* rbuf, int* tags) {
    int i = blockIdx.x * blockDim.x + threadIdx.x;
    if (i < HID)
        __hip_atomic_store(&rbuf[i], rate[i], __ATOMIC_RELAXED, __HIP_MEMORY_SCOPE_AGENT);
    if (i < NTAGS)
        __hip_atomic_store(&tags[i], 0, __ATOMIC_RELAXED, __HIP_MEMORY_SCOPE_AGENT);
}

// ---------------------------------------------------------------------------
// xproj[h, t] = sum_i Wi[h,i] * sig[i,t] + bi[h]   -> written to out2 (H,T)
// grid (T/512, H/32), block 256. Each thread: 2 t's, 32 h's.
// ---------------------------------------------------------------------------
__global__ void __launch_bounds__(256) k_xproj(const float* __restrict__ sig,
                                               const float* __restrict__ Wi,
                                               const float* __restrict__ bi,
                                               float* __restrict__ out2) {
    __shared__ float wl[32 * IN_SZ];  // 32 KB
    const int tid = threadIdx.x;
    const int t0 = blockIdx.x * 512;
    const int h0 = blockIdx.y * 32;

    // stage Wi rows h0..h0+31 (contiguous 8192 floats)
    {
        const float4* s4 = (const float4*)(Wi + (size_t)h0 * IN_SZ);
        float4* d4 = (float4*)wl;
        #pragma unroll
        for (int k = 0; k < 8; ++k) d4[tid + k * 256] = s4[tid + k * 256];
    }
    __syncthreads();

    const int t1 = t0 + tid, t2 = t1 + 256;
    float acc1[32], acc2[32];
    #pragma unroll
    for (int j = 0; j < 32; ++j) { acc1[j] = 0.f; acc2[j] = 0.f; }

    for (int i = 0; i < IN_SZ; ++i) {
        float s1 = sig[(size_t)i * T_STEPS + t1];
        float s2 = sig[(size_t)i * T_STEPS + t2];
        #pragma unroll
        for (int j = 0; j < 32; ++j) {
            float w = wl[j * IN_SZ + i];
            acc1[j] = fmaf(w, s1, acc1[j]);
            acc2[j] = fmaf(w, s2, acc2[j]);
        }
    }
    #pragma unroll
    for (int j = 0; j < 32; ++j) {
        float b = bi[h0 + j];
        out2[(size_t)(h0 + j) * T_STEPS + t1] = acc1[j] + b;
        out2[(size_t)(h0 + j) * T_STEPS + t2] = acc2[j] + b;
    }
}

// ---------------------------------------------------------------------------
// Persistent scan. 256 blocks x 256 threads (cooperative). Block b owns rows
// h0 = b*8 .. +7; wave w owns rows h0+2w, h0+2w+1; Wh slice lives in LDS.
// Skew-1 tag protocol: tag[g] = #steps produced by wave g (monotonic).
// Before consuming r_t each WG polls all tags >= t; depth-3 ring is safe.
// ---------------------------------------------------------------------------
__global__ void __launch_bounds__(256) k_scan(const float* __restrict__ Wh,
                                              const float* __restrict__ bh,
                                              const float* __restrict__ rate0,
                                              float* __restrict__ out2,
                                              float* rbuf, int* tags) {
    __shared__ float whs[RPB * HID];  // 64 KB
    __shared__ float rl[HID];         // 8 KB
    const int tid  = threadIdx.x;
    const int bid  = blockIdx.x;
    const int w    = tid >> 6;
    const int lane = tid & 63;
    const int h0   = bid * RPB;
    const int ra   = h0 + 2 * w;
    const int rb   = ra + 1;
    const int mytag = bid * 4 + w;

    // stage Wh rows (contiguous RPB*HID floats), coalesced float4
    {
        const float4* s4 = (const float4*)(Wh + (size_t)h0 * HID);
        float4* d4 = (float4*)whs;
        #pragma unroll
        for (int k = 0; k < RPB * HID / 4 / 256; ++k)
            d4[tid + k * 256] = s4[tid + k * 256];
    }
    float rolda = rate0[ra], roldb = rate0[rb];
    const float bha = bh[ra], bhb = bh[rb];
    __syncthreads();

    int cur = 0;  // t % 3
    for (int t = 0; t < T_STEPS; ++t) {
        // ---- poll: all 1024 wave-tags >= t ----
        for (;;) {
            int ok = 1;
            #pragma unroll
            for (int q = 0; q < 4; ++q) {
                int v = __hip_atomic_load(&tags[tid + q * 256],
                                          __ATOMIC_RELAXED, __HIP_MEMORY_SCOPE_AGENT);
                ok &= (v >= t);
            }
            if (__syncthreads_and(ok)) break;
            __builtin_amdgcn_s_sleep(1);
        }
        __threadfence();  // acquire: order poll before r loads

        // ---- stage r_t into LDS (L2-bypassing 8B atomic loads) ----
        {
            const float* src = rbuf + cur * HID;
            #pragma unroll
            for (int q = 0; q < 4; ++q) {
                int k = tid * 2 + q * 512;
                u64 u = __hip_atomic_load((u64*)(src + k),
                                          __ATOMIC_RELAXED, __HIP_MEMORY_SCOPE_AGENT);
                *(u64*)(&rl[k]) = u;
            }
        }
        __syncthreads();

        // ---- two dot products per wave (conflict-free b128 reads) ----
        float p0 = 0.f, p1 = 0.f;
        {
            const float4* r4 = (const float4*)rl;
            const float4* a4 = (const float4*)(whs + (size_t)(2 * w) * HID);
            const float4* b4 = (const float4*)(whs + (size_t)(2 * w + 1) * HID);
            #pragma unroll
            for (int c = 0; c < 8; ++c) {
                float4 rv = r4[c * 64 + lane];
                float4 av = a4[c * 64 + lane];
                float4 bv = b4[c * 64 + lane];
                p0 = fmaf(rv.x, av.x, p0); p0 = fmaf(rv.y, av.y, p0);
                p0 = fmaf(rv.z, av.z, p0); p0 = fmaf(rv.w, av.w, p0);
                p1 = fmaf(rv.x, bv.x, p1); p1 = fmaf(rv.y, bv.y, p1);
                p1 = fmaf(rv.z, bv.z, p1); p1 = fmaf(rv.w, bv.w, p1);
            }
        }
        #pragma unroll
        for (int off = 32; off >= 1; off >>= 1) {
            p0 += __shfl_xor(p0, off, 64);
            p1 += __shfl_xor(p1, off, 64);
        }

        const int nxt = (cur == 2) ? 0 : cur + 1;
        if (lane == 0) {
            size_t ia = (size_t)ra * T_STEPS + t;
            size_t ib = (size_t)rb * T_STEPS + t;
            float va = p0 + out2[ia] + bha;   // xp read (then overwritten)
            float vb = p1 + out2[ib] + bhb;
            float rna = 0.9f * rolda + 0.1f * tanhf(va);
            float rnb = 0.9f * roldb + 0.1f * tanhf(vb);
            out2[ia] = rna;                    // rate_all output
            out2[ib] = rnb;
            float* dst = rbuf + nxt * HID;
            __hip_atomic_store(&dst[ra], rna, __ATOMIC_RELAXED, __HIP_MEMORY_SCOPE_AGENT);
            __hip_atomic_store(&dst[rb], rnb, __ATOMIC_RELAXED, __HIP_MEMORY_SCOPE_AGENT);
            __hip_atomic_store(&tags[mytag], t + 1, __ATOMIC_RELEASE, __HIP_MEMORY_SCOPE_AGENT);
            rolda = rna; roldb = rnb;
        }
        cur = nxt;
    }
}

// ---------------------------------------------------------------------------
// logits[t,o] = sum_h rates[t,h]*Wo[o,h] + bo[o]; out0[o,t] = logsoftmax_o.
// grid 64, block 512 (8 waves). Wave w -> o in [16w,16w+16); lane -> t0+lane
// and t0+64+lane (t-tile = 128).
// ---------------------------------------------------------------------------
__global__ void __launch_bounds__(512) k_logits(const float* __restrict__ out2,
                                                const float* __restrict__ Wo,
                                                const float* __restrict__ bo,
                                                float* __restrict__ out0) {
    __shared__ float wos[128 * 128];  // 64 KB
    __shared__ float red[8 * 128];    // 4 KB
    __shared__ float fin[128];
    const int tid  = threadIdx.x;
    const int w    = tid >> 6;
    const int lane = tid & 63;
    const int t0   = blockIdx.x * 128;
    const int ob   = w * 16;

    float acc0[16], acc1[16];
    #pragma unroll
    for (int j = 0; j < 16; ++j) { acc0[j] = 0.f; acc1[j] = 0.f; }

    for (int hb = 0; hb < HID / 128; ++hb) {
        __syncthreads();  // protect previous tile reads
        {
            const float4* wo4 = (const float4*)Wo;
            float4* ws4 = (float4*)wos;
            #pragma unroll
            for (int k = 0; k < 8; ++k) {
                int g = tid + k * 512;            // 0..4095 float4s
                int o = g >> 5;                    // 32 float4 per 128-col row
                int c = g & 31;
                ws4[g] = wo4[(size_t)o * (HID / 4) + hb * 32 + c];
            }
        }
        __syncthreads();
        for (int hh = 0; hh < 128; ++hh) {
            int h = hb * 128 + hh;
            float rA = out2[(size_t)h * T_STEPS + t0 + lane];
            float rB = out2[(size_t)h * T_STEPS + t0 + 64 + lane];
            #pragma unroll
            for (int j = 0; j < 16; ++j) {
                float wv = wos[(ob + j) * 128 + hh];
                acc0[j] = fmaf(wv, rA, acc0[j]);
                acc1[j] = fmaf(wv, rB, acc1[j]);
            }
        }
    }
    #pragma unroll
    for (int j = 0; j < 16; ++j) {
        float b = bo[ob + j];
        acc0[j] += b; acc1[j] += b;
    }

    // --- logsoftmax over o (128 values spread over 8 waves) ---
    float m0 = acc0[0], m1 = acc1[0];
    #pragma unroll
    for (int j = 1; j < 16; ++j) { m0 = fmaxf(m0, acc0[j]); m1 = fmaxf(m1, acc1[j]); }
    red[w * 128 + lane] = m0;
    red[w * 128 + 64 + lane] = m1;
    __syncthreads();
    if (tid < 128) {
        float m = red[tid];
        #pragma unroll
        for (int q = 1; q < 8; ++q) m = fmaxf(m, red[q * 128 + tid]);
        fin[tid] = m;
    }
    __syncthreads();
    float fm0 = fin[lane], fm1 = fin[64 + lane];
    float s0 = 0.f, s1 = 0.f;
    #pragma unroll
    for (int j = 0; j < 16; ++j) {
        s0 += expf(acc0[j] - fm0);
        s1 += expf(acc1[j] - fm1);
    }
    red[w * 128 + lane] = s0;
    red[w * 128 + 64 + lane] = s1;
    __syncthreads();
    if (tid < 128) {
        float s = 0.f;
        #pragma unroll
        for (int q = 0; q < 8; ++q) s += red[q * 128 + tid];
        fin[tid] = fin[tid] + logf(s);   // logsumexp
    }
    __syncthreads();
    float L0 = fin[lane], L1 = fin[64 + lane];
    #pragma unroll
    for (int j = 0; j < 16; ++j) {
        out0[(size_t)(ob + j) * T_STEPS + t0 + lane]      = acc0[j] - L0;
        out0[(size_t)(ob + j) * T_STEPS + t0 + 64 + lane] = acc1[j] - L1;
    }
}

// ---------------------------------------------------------------------------
extern "C" void kernel_launch(void* const* d_in, const int* in_sizes, int n_in,
                              void* d_out, int out_size, void* d_ws, size_t ws_size,
                              hipStream_t stream) {
    const float* sig  = (const float*)d_in[0];
    const float* rate = (const float*)d_in[1];
    const float* Wi   = (const float*)d_in[2];
    const float* bi   = (const float*)d_in[3];
    const float* Wh   = (const float*)d_in[4];
    const float* bh   = (const float*)d_in[5];
    const float* Wo   = (const float*)d_in[6];
    const float* bo   = (const float*)d_in[7];

    float* out0 = (float*)d_out;                       // (128, 8192) logsoftmax
    float* out2 = out0 + (size_t)OUT_SZ * T_STEPS;     // (2048, 8192) rate_all

    float* rbuf = (float*)d_ws;                        // 3*HID floats
    int*   tags = (int*)((char*)d_ws + 3 * HID * sizeof(float));

    hipLaunchKernelGGL(k_init, dim3(8), dim3(256), 0, stream, rate, rbuf, tags);
    hipLaunchKernelGGL(k_xproj, dim3(T_STEPS / 512, HID / 32), dim3(256), 0, stream,
                       sig, Wi, bi, out2);

    void* args[] = {(void*)&Wh, (void*)&bh, (void*)&rate,
                    (void*)&out2, (void*)&rbuf, (void*)&tags};
    hipLaunchCooperativeKernel((const void*)k_scan, dim3(NBLK), dim3(256),
                               args, 0, stream);

    hipLaunchKernelGGL(k_logits, dim3(T_STEPS / 128), dim3(512), 0, stream,
                       out2, Wo, bo, out0);
}

// Round 2
// 49978.125 us; speedup vs baseline: 5.0825x; 5.0825x over previous
//
#include <hip/hip_runtime.h>
#include <math.h>

#define T_STEPS 8192
#define HID     2048
#define IN_SZ   256
#define OUT_SZ  128
#define NBLK    256            // scan workgroups (1 per CU)
#define RPB     8              // rows per workgroup = HID/NBLK
#define NTAGS   NBLK           // one tag per block

typedef unsigned long long u64;

// ---------------------------------------------------------------------------
// ws layout: [0, 3*HID) floats = r ring buffer (depth 3); then NTAGS ints.
// All cross-block traffic uses agent-scope relaxed atomics (sc1, L2-bypass,
// served at the device coherence point). NO release/acquire fences: they
// lower to buffer_wbl2/buffer_inv (full L2 writeback/invalidate) on gfx950
// and cost ~30us/step across 256 blocks. Ordering is provided by the
// vmcnt(0) drain that __syncthreads performs before s_barrier.
// ---------------------------------------------------------------------------

__global__ void k_init(const float* __restrict__ rate, float* rbuf, int* tags) {
    int i = blockIdx.x * blockDim.x + threadIdx.x;
    if (i < HID)
        __hip_atomic_store(&rbuf[i], rate[i], __ATOMIC_RELAXED, __HIP_MEMORY_SCOPE_AGENT);
    if (i < NTAGS)
        __hip_atomic_store(&tags[i], 0, __ATOMIC_RELAXED, __HIP_MEMORY_SCOPE_AGENT);
}

// ---------------------------------------------------------------------------
// xproj[h, t] = sum_i Wi[h,i] * sig[i,t] + bi[h]   -> written to out2 (H,T)
// ---------------------------------------------------------------------------
__global__ void __launch_bounds__(256) k_xproj(const float* __restrict__ sig,
                                               const float* __restrict__ Wi,
                                               const float* __restrict__ bi,
                                               float* __restrict__ out2) {
    __shared__ float wl[32 * IN_SZ];  // 32 KB
    const int tid = threadIdx.x;
    const int t0 = blockIdx.x * 512;
    const int h0 = blockIdx.y * 32;

    {
        const float4* s4 = (const float4*)(Wi + (size_t)h0 * IN_SZ);
        float4* d4 = (float4*)wl;
        #pragma unroll
        for (int k = 0; k < 8; ++k) d4[tid + k * 256] = s4[tid + k * 256];
    }
    __syncthreads();

    const int t1 = t0 + tid, t2 = t1 + 256;
    float acc1[32], acc2[32];
    #pragma unroll
    for (int j = 0; j < 32; ++j) { acc1[j] = 0.f; acc2[j] = 0.f; }

    for (int i = 0; i < IN_SZ; ++i) {
        float s1 = sig[(size_t)i * T_STEPS + t1];
        float s2 = sig[(size_t)i * T_STEPS + t2];
        #pragma unroll
        for (int j = 0; j < 32; ++j) {
            float w = wl[j * IN_SZ + i];
            acc1[j] = fmaf(w, s1, acc1[j]);
            acc2[j] = fmaf(w, s2, acc2[j]);
        }
    }
    #pragma unroll
    for (int j = 0; j < 32; ++j) {
        float b = bi[h0 + j];
        out2[(size_t)(h0 + j) * T_STEPS + t1] = acc1[j] + b;
        out2[(size_t)(h0 + j) * T_STEPS + t2] = acc2[j] + b;
    }
}

// ---------------------------------------------------------------------------
// Persistent scan. 256 blocks x 256 threads (cooperative). Block b owns rows
// h0 = b*8 .. +7; wave w owns rows h0+2w, h0+2w+1; Wh slice lives in LDS.
// Per-block tag protocol: tags[b] = #steps block b has produced.
// Skew between any two blocks is <=1 step => depth-3 ring is safe.
// ---------------------------------------------------------------------------
__global__ void __launch_bounds__(256) k_scan(const float* __restrict__ Wh,
                                              const float* __restrict__ bh,
                                              const float* __restrict__ rate0,
                                              float* __restrict__ out2,
                                              float* rbuf, int* tags) {
    __shared__ float whs[RPB * HID];  // 64 KB
    __shared__ float rl[HID];         // 8 KB
    const int tid  = threadIdx.x;
    const int bid  = blockIdx.x;
    const int w    = tid >> 6;
    const int lane = tid & 63;
    const int h0   = bid * RPB;
    const int ra   = h0 + 2 * w;
    const int rb   = ra + 1;

    {
        const float4* s4 = (const float4*)(Wh + (size_t)h0 * HID);
        float4* d4 = (float4*)whs;
        #pragma unroll
        for (int k = 0; k < RPB * HID / 4 / 256; ++k)
            d4[tid + k * 256] = s4[tid + k * 256];
    }
    float rolda = rate0[ra], roldb = rate0[rb];
    const float bha = bh[ra], bhb = bh[rb];
    __syncthreads();

    int cur = 0;  // t % 3
    for (int t = 0; t < T_STEPS; ++t) {
        // ---- prefetch xp for this step (independent of r_t; hides under poll)
        const size_t ia = (size_t)ra * T_STEPS + t;
        const size_t ib = (size_t)rb * T_STEPS + t;
        float xpa = 0.f, xpb = 0.f;
        if (lane == 0) { xpa = out2[ia]; xpb = out2[ib]; }

        // ---- poll: all 256 block-tags >= t (1 tag per thread) ----
        for (;;) {
            int v = __hip_atomic_load(&tags[tid], __ATOMIC_RELAXED,
                                      __HIP_MEMORY_SCOPE_AGENT);
            if (__syncthreads_and(v >= t)) break;
        }

        // ---- stage r_t into LDS (L2-bypassing 8B atomic loads) ----
        {
            const float* src = rbuf + cur * HID;
            #pragma unroll
            for (int q = 0; q < 4; ++q) {
                int k = tid * 2 + q * 512;
                u64 u = __hip_atomic_load((u64*)(src + k),
                                          __ATOMIC_RELAXED, __HIP_MEMORY_SCOPE_AGENT);
                *(u64*)(&rl[k]) = u;
            }
        }
        __syncthreads();

        // ---- two dot products per wave (conflict-free b128 reads) ----
        float p0 = 0.f, p1 = 0.f;
        {
            const float4* r4 = (const float4*)rl;
            const float4* a4 = (const float4*)(whs + (size_t)(2 * w) * HID);
            const float4* b4 = (const float4*)(whs + (size_t)(2 * w + 1) * HID);
            #pragma unroll
            for (int c = 0; c < 8; ++c) {
                float4 rv = r4[c * 64 + lane];
                float4 av = a4[c * 64 + lane];
                float4 bv = b4[c * 64 + lane];
                p0 = fmaf(rv.x, av.x, p0); p0 = fmaf(rv.y, av.y, p0);
                p0 = fmaf(rv.z, av.z, p0); p0 = fmaf(rv.w, av.w, p0);
                p1 = fmaf(rv.x, bv.x, p1); p1 = fmaf(rv.y, bv.y, p1);
                p1 = fmaf(rv.z, bv.z, p1); p1 = fmaf(rv.w, bv.w, p1);
            }
        }
        #pragma unroll
        for (int off = 32; off >= 1; off >>= 1) {
            p0 += __shfl_xor(p0, off, 64);
            p1 += __shfl_xor(p1, off, 64);
        }

        const int nxt = (cur == 2) ? 0 : cur + 1;
        if (lane == 0) {
            float va = p0 + xpa + bha;
            float vb = p1 + xpb + bhb;
            float rna = 0.9f * rolda + 0.1f * tanhf(va);
            float rnb = 0.9f * roldb + 0.1f * tanhf(vb);
            out2[ia] = rna;                    // rate_all output (plain, cached)
            out2[ib] = rnb;
            // packed 8B store of (rna, rnb) to ring slot nxt
            float2 pk; pk.x = rna; pk.y = rnb;
            __hip_atomic_store((u64*)(rbuf + nxt * HID + ra), *(u64*)&pk,
                               __ATOMIC_RELAXED, __HIP_MEMORY_SCOPE_AGENT);
            rolda = rna; roldb = rnb;
        }
        // barrier drains vmcnt(0) per wave -> all r stores are at the
        // coherence point before any thread passes
        __syncthreads();
        if (tid == 0) {
            asm volatile("s_waitcnt vmcnt(0)" ::: "memory");
            __hip_atomic_store(&tags[bid], t + 1, __ATOMIC_RELAXED,
                               __HIP_MEMORY_SCOPE_AGENT);
        }
        cur = nxt;
    }
}

// ---------------------------------------------------------------------------
// logits[t,o] = sum_h rates[t,h]*Wo[o,h] + bo[o]; out0[o,t] = logsoftmax_o.
// ---------------------------------------------------------------------------
__global__ void __launch_bounds__(512) k_logits(const float* __restrict__ out2,
                                                const float* __restrict__ Wo,
                                                const float* __restrict__ bo,
                                                float* __restrict__ out0) {
    __shared__ float wos[128 * 128];  // 64 KB
    __shared__ float red[8 * 128];    // 4 KB
    __shared__ float fin[128];
    const int tid  = threadIdx.x;
    const int w    = tid >> 6;
    const int lane = tid & 63;
    const int t0   = blockIdx.x * 128;
    const int ob   = w * 16;

    float acc0[16], acc1[16];
    #pragma unroll
    for (int j = 0; j < 16; ++j) { acc0[j] = 0.f; acc1[j] = 0.f; }

    for (int hb = 0; hb < HID / 128; ++hb) {
        __syncthreads();
        {
            const float4* wo4 = (const float4*)Wo;
            float4* ws4 = (float4*)wos;
            #pragma unroll
            for (int k = 0; k < 8; ++k) {
                int g = tid + k * 512;
                int o = g >> 5;
                int c = g & 31;
                ws4[g] = wo4[(size_t)o * (HID / 4) + hb * 32 + c];
            }
        }
        __syncthreads();
        for (int hh = 0; hh < 128; ++hh) {
            int h = hb * 128 + hh;
            float rA = out2[(size_t)h * T_STEPS + t0 + lane];
            float rB = out2[(size_t)h * T_STEPS + t0 + 64 + lane];
            #pragma unroll
            for (int j = 0; j < 16; ++j) {
                float wv = wos[(ob + j) * 128 + hh];
                acc0[j] = fmaf(wv, rA, acc0[j]);
                acc1[j] = fmaf(wv, rB, acc1[j]);
            }
        }
    }
    #pragma unroll
    for (int j = 0; j < 16; ++j) {
        float b = bo[ob + j];
        acc0[j] += b; acc1[j] += b;
    }

    float m0 = acc0[0], m1 = acc1[0];
    #pragma unroll
    for (int j = 1; j < 16; ++j) { m0 = fmaxf(m0, acc0[j]); m1 = fmaxf(m1, acc1[j]); }
    red[w * 128 + lane] = m0;
    red[w * 128 + 64 + lane] = m1;
    __syncthreads();
    if (tid < 128) {
        float m = red[tid];
        #pragma unroll
        for (int q = 1; q < 8; ++q) m = fmaxf(m, red[q * 128 + tid]);
        fin[tid] = m;
    }
    __syncthreads();
    float fm0 = fin[lane], fm1 = fin[64 + lane];
    float s0 = 0.f, s1 = 0.f;
    #pragma unroll
    for (int j = 0; j < 16; ++j) {
        s0 += expf(acc0[j] - fm0);
        s1 += expf(acc1[j] - fm1);
    }
    red[w * 128 + lane] = s0;
    red[w * 128 + 64 + lane] = s1;
    __syncthreads();
    if (tid < 128) {
        float s = 0.f;
        #pragma unroll
        for (int q = 0; q < 8; ++q) s += red[q * 128 + tid];
        fin[tid] = fin[tid] + logf(s);
    }
    __syncthreads();
    float L0 = fin[lane], L1 = fin[64 + lane];
    #pragma unroll
    for (int j = 0; j < 16; ++j) {
        out0[(size_t)(ob + j) * T_STEPS + t0 + lane]      = acc0[j] - L0;
        out0[(size_t)(ob + j) * T_STEPS + t0 + 64 + lane] = acc1[j] - L1;
    }
}

// ---------------------------------------------------------------------------
extern "C" void kernel_launch(void* const* d_in, const int* in_sizes, int n_in,
                              void* d_out, int out_size, void* d_ws, size_t ws_size,
                              hipStream_t stream) {
    const float* sig  = (const float*)d_in[0];
    const float* rate = (const float*)d_in[1];
    const float* Wi   = (const float*)d_in[2];
    const float* bi   = (const float*)d_in[3];
    const float* Wh   = (const float*)d_in[4];
    const float* bh   = (const float*)d_in[5];
    const float* Wo   = (const float*)d_in[6];
    const float* bo   = (const float*)d_in[7];

    float* out0 = (float*)d_out;                       // (128, 8192) logsoftmax
    float* out2 = out0 + (size_t)OUT_SZ * T_STEPS;     // (2048, 8192) rate_all

    float* rbuf = (float*)d_ws;                        // 3*HID floats
    int*   tags = (int*)((char*)d_ws + 3 * HID * sizeof(float));

    hipLaunchKernelGGL(k_init, dim3(8), dim3(256), 0, stream, rate, rbuf, tags);
    hipLaunchKernelGGL(k_xproj, dim3(T_STEPS / 512, HID / 32), dim3(256), 0, stream,
                       sig, Wi, bi, out2);

    void* args[] = {(void*)&Wh, (void*)&bh, (void*)&rate,
                    (void*)&out2, (void*)&rbuf, (void*)&tags};
    hipLaunchCooperativeKernel((const void*)k_scan, dim3(NBLK), dim3(256),
                               args, 0, stream);

    hipLaunchKernelGGL(k_logits, dim3(T_STEPS / 128), dim3(512), 0, stream,
                       out2, Wo, bo, out0);
}

// Round 3
// 32898.077 us; speedup vs baseline: 7.7212x; 1.5192x over previous
//
#include <hip/hip_runtime.h>
#include <math.h>

#define T_STEPS 8192
#define HID     2048
#define IN_SZ   256
#define OUT_SZ  128
#define NBLK    256            // scan workgroups (1 per CU)
#define RPB     8              // rows per workgroup = HID/NBLK

typedef unsigned long long u64;

// ---------------------------------------------------------------------------
// ws layout: u64 ring[3][HID]. Entry = (tag<<32) | float_bits. Slot t%3 holds
// r_t tagged t. Producers fire-and-forget 8B agent-scope stores; consumers
// spin on exactly the entries they stage (arrival check == data fetch), so
// there is NO separate tag, NO vmcnt drain, NO rendezvous barrier.
// Skew between blocks is <=1 step (can't produce t+1 without all of t), so
// a depth-3 ring never aliases; stale tags from a prior replay (8190..8192)
// are overwritten thousands of steps before they could match.
// ---------------------------------------------------------------------------

__global__ void k_init(const float* __restrict__ rate, u64* ring) {
    int i = blockIdx.x * blockDim.x + threadIdx.x;
    if (i < HID) {
        // slot 0 holds r_0 with tag 0
        __hip_atomic_store(&ring[i], (u64)__float_as_uint(rate[i]),
                           __ATOMIC_RELAXED, __HIP_MEMORY_SCOPE_AGENT);
        // scrub slots 1,2 with a tag no step ever expects
        __hip_atomic_store(&ring[HID + i], 0xFFFFFFFF00000000ull,
                           __ATOMIC_RELAXED, __HIP_MEMORY_SCOPE_AGENT);
        __hip_atomic_store(&ring[2 * HID + i], 0xFFFFFFFF00000000ull,
                           __ATOMIC_RELAXED, __HIP_MEMORY_SCOPE_AGENT);
    }
}

// ---------------------------------------------------------------------------
// xproj[h, t] = sum_i Wi[h,i] * sig[i,t] + bi[h]   -> written to out2 (H,T)
// ---------------------------------------------------------------------------
__global__ void __launch_bounds__(256) k_xproj(const float* __restrict__ sig,
                                               const float* __restrict__ Wi,
                                               const float* __restrict__ bi,
                                               float* __restrict__ out2) {
    __shared__ float wl[32 * IN_SZ];  // 32 KB
    const int tid = threadIdx.x;
    const int t0 = blockIdx.x * 512;
    const int h0 = blockIdx.y * 32;

    {
        const float4* s4 = (const float4*)(Wi + (size_t)h0 * IN_SZ);
        float4* d4 = (float4*)wl;
        #pragma unroll
        for (int k = 0; k < 8; ++k) d4[tid + k * 256] = s4[tid + k * 256];
    }
    __syncthreads();

    const int t1 = t0 + tid, t2 = t1 + 256;
    float acc1[32], acc2[32];
    #pragma unroll
    for (int j = 0; j < 32; ++j) { acc1[j] = 0.f; acc2[j] = 0.f; }

    for (int i = 0; i < IN_SZ; ++i) {
        float s1 = sig[(size_t)i * T_STEPS + t1];
        float s2 = sig[(size_t)i * T_STEPS + t2];
        #pragma unroll
        for (int j = 0; j < 32; ++j) {
            float w = wl[j * IN_SZ + i];
            acc1[j] = fmaf(w, s1, acc1[j]);
            acc2[j] = fmaf(w, s2, acc2[j]);
        }
    }
    #pragma unroll
    for (int j = 0; j < 32; ++j) {
        float b = bi[h0 + j];
        out2[(size_t)(h0 + j) * T_STEPS + t1] = acc1[j] + b;
        out2[(size_t)(h0 + j) * T_STEPS + t2] = acc2[j] + b;
    }
}

// ---------------------------------------------------------------------------
// Persistent scan. 256 blocks x 256 threads (cooperative). Block b owns rows
// h0 = b*8 .. +7; wave w owns rows h0+2w, h0+2w+1; Wh slice lives in LDS.
// Per step: each thread spins on its 8 tagged ring entries, stages to LDS,
// one barrier, dot+reduce, lane0 produces 2 tagged entries. No other sync.
// ---------------------------------------------------------------------------
__global__ void __launch_bounds__(256) k_scan(const float* __restrict__ Wh,
                                              const float* __restrict__ bh,
                                              const float* __restrict__ rate0,
                                              float* __restrict__ out2,
                                              u64* ring) {
    __shared__ float whs[RPB * HID];  // 64 KB
    __shared__ float rl[HID];         // 8 KB
    const int tid  = threadIdx.x;
    const int bid  = blockIdx.x;
    const int w    = tid >> 6;
    const int lane = tid & 63;
    const int h0   = bid * RPB;
    const int ra   = h0 + 2 * w;
    const int rb   = ra + 1;

    {
        const float4* s4 = (const float4*)(Wh + (size_t)h0 * HID);
        float4* d4 = (float4*)whs;
        #pragma unroll
        for (int k = 0; k < RPB * HID / 4 / 256; ++k)
            d4[tid + k * 256] = s4[tid + k * 256];
    }
    const float bha = bh[ra], bhb = bh[rb];
    __syncthreads();

    int cur = 0;  // t % 3
    for (int t = 0; t < T_STEPS; ++t) {
        // ---- prefetch xp for this step (hides under the poll) ----
        const size_t ia = (size_t)ra * T_STEPS + t;
        const size_t ib = (size_t)rb * T_STEPS + t;
        float xpa = 0.f, xpb = 0.f;
        if (lane == 0) { xpa = out2[ia]; xpb = out2[ib]; }

        // ---- spin on my 8 tagged entries of slot cur (tag must == t) ----
        {
            const u64* src = ring + (size_t)cur * HID;
            u64 vals[8];
            unsigned pend = 0xFFu;
            while (pend) {
                #pragma unroll
                for (int q = 0; q < 8; ++q) {
                    if (pend & (1u << q))
                        vals[q] = __hip_atomic_load(&src[tid + q * 256],
                                                    __ATOMIC_RELAXED,
                                                    __HIP_MEMORY_SCOPE_AGENT);
                }
                #pragma unroll
                for (int q = 0; q < 8; ++q) {
                    if ((pend & (1u << q)) &&
                        (unsigned)(vals[q] >> 32) == (unsigned)t)
                        pend &= ~(1u << q);
                }
            }
            #pragma unroll
            for (int q = 0; q < 8; ++q)
                rl[tid + q * 256] = __uint_as_float((unsigned)vals[q]);
        }
        __syncthreads();

        // ---- two dot products per wave (conflict-free b128 reads) ----
        float p0 = 0.f, p1 = 0.f;
        {
            const float4* r4 = (const float4*)rl;
            const float4* a4 = (const float4*)(whs + (size_t)(2 * w) * HID);
            const float4* b4 = (const float4*)(whs + (size_t)(2 * w + 1) * HID);
            #pragma unroll
            for (int c = 0; c < 8; ++c) {
                float4 rv = r4[c * 64 + lane];
                float4 av = a4[c * 64 + lane];
                float4 bv = b4[c * 64 + lane];
                p0 = fmaf(rv.x, av.x, p0); p0 = fmaf(rv.y, av.y, p0);
                p0 = fmaf(rv.z, av.z, p0); p0 = fmaf(rv.w, av.w, p0);
                p1 = fmaf(rv.x, bv.x, p1); p1 = fmaf(rv.y, bv.y, p1);
                p1 = fmaf(rv.z, bv.z, p1); p1 = fmaf(rv.w, bv.w, p1);
            }
        }
        #pragma unroll
        for (int off = 32; off >= 1; off >>= 1) {
            p0 += __shfl_xor(p0, off, 64);
            p1 += __shfl_xor(p1, off, 64);
        }

        const int nxt = (cur == 2) ? 0 : cur + 1;
        if (lane == 0) {
            float rolda = __uint_as_float(__float_as_uint(rl[ra]));  // r_t own rows
            float roldb = rl[rb];
            float va = p0 + xpa + bha;
            float vb = p1 + xpb + bhb;
            float rna = 0.9f * rolda + 0.1f * tanhf(va);
            float rnb = 0.9f * roldb + 0.1f * tanhf(vb);
            out2[ia] = rna;                    // rate_all output (plain, cached)
            out2[ib] = rnb;
            u64* dst = ring + (size_t)nxt * HID;
            const u64 tagbits = (u64)(unsigned)(t + 1) << 32;
            __hip_atomic_store(&dst[ra], tagbits | __float_as_uint(rna),
                               __ATOMIC_RELAXED, __HIP_MEMORY_SCOPE_AGENT);
            __hip_atomic_store(&dst[rb], tagbits | __float_as_uint(rnb),
                               __ATOMIC_RELAXED, __HIP_MEMORY_SCOPE_AGENT);
        }
        cur = nxt;
    }
}

// ---------------------------------------------------------------------------
// logits[t,o] = sum_h rates[t,h]*Wo[o,h] + bo[o]; out0[o,t] = logsoftmax_o.
// ---------------------------------------------------------------------------
__global__ void __launch_bounds__(512) k_logits(const float* __restrict__ out2,
                                                const float* __restrict__ Wo,
                                                const float* __restrict__ bo,
                                                float* __restrict__ out0) {
    __shared__ float wos[128 * 128];  // 64 KB
    __shared__ float red[8 * 128];    // 4 KB
    __shared__ float fin[128];
    const int tid  = threadIdx.x;
    const int w    = tid >> 6;
    const int lane = tid & 63;
    const int t0   = blockIdx.x * 128;
    const int ob   = w * 16;

    float acc0[16], acc1[16];
    #pragma unroll
    for (int j = 0; j < 16; ++j) { acc0[j] = 0.f; acc1[j] = 0.f; }

    for (int hb = 0; hb < HID / 128; ++hb) {
        __syncthreads();
        {
            const float4* wo4 = (const float4*)Wo;
            float4* ws4 = (float4*)wos;
            #pragma unroll
            for (int k = 0; k < 8; ++k) {
                int g = tid + k * 512;
                int o = g >> 5;
                int c = g & 31;
                ws4[g] = wo4[(size_t)o * (HID / 4) + hb * 32 + c];
            }
        }
        __syncthreads();
        for (int hh = 0; hh < 128; ++hh) {
            int h = hb * 128 + hh;
            float rA = out2[(size_t)h * T_STEPS + t0 + lane];
            float rB = out2[(size_t)h * T_STEPS + t0 + 64 + lane];
            #pragma unroll
            for (int j = 0; j < 16; ++j) {
                float wv = wos[(ob + j) * 128 + hh];
                acc0[j] = fmaf(wv, rA, acc0[j]);
                acc1[j] = fmaf(wv, rB, acc1[j]);
            }
        }
    }
    #pragma unroll
    for (int j = 0; j < 16; ++j) {
        float b = bo[ob + j];
        acc0[j] += b; acc1[j] += b;
    }

    float m0 = acc0[0], m1 = acc1[0];
    #pragma unroll
    for (int j = 1; j < 16; ++j) { m0 = fmaxf(m0, acc0[j]); m1 = fmaxf(m1, acc1[j]); }
    red[w * 128 + lane] = m0;
    red[w * 128 + 64 + lane] = m1;
    __syncthreads();
    if (tid < 128) {
        float m = red[tid];
        #pragma unroll
        for (int q = 1; q < 8; ++q) m = fmaxf(m, red[q * 128 + tid]);
        fin[tid] = m;
    }
    __syncthreads();
    float fm0 = fin[lane], fm1 = fin[64 + lane];
    float s0 = 0.f, s1 = 0.f;
    #pragma unroll
    for (int j = 0; j < 16; ++j) {
        s0 += expf(acc0[j] - fm0);
        s1 += expf(acc1[j] - fm1);
    }
    red[w * 128 + lane] = s0;
    red[w * 128 + 64 + lane] = s1;
    __syncthreads();
    if (tid < 128) {
        float s = 0.f;
        #pragma unroll
        for (int q = 0; q < 8; ++q) s += red[q * 128 + tid];
        fin[tid] = fin[tid] + logf(s);
    }
    __syncthreads();
    float L0 = fin[lane], L1 = fin[64 + lane];
    #pragma unroll
    for (int j = 0; j < 16; ++j) {
        out0[(size_t)(ob + j) * T_STEPS + t0 + lane]      = acc0[j] - L0;
        out0[(size_t)(ob + j) * T_STEPS + t0 + 64 + lane] = acc1[j] - L1;
    }
}

// ---------------------------------------------------------------------------
extern "C" void kernel_launch(void* const* d_in, const int* in_sizes, int n_in,
                              void* d_out, int out_size, void* d_ws, size_t ws_size,
                              hipStream_t stream) {
    const float* sig  = (const float*)d_in[0];
    const float* rate = (const float*)d_in[1];
    const float* Wi   = (const float*)d_in[2];
    const float* bi   = (const float*)d_in[3];
    const float* Wh   = (const float*)d_in[4];
    const float* bh   = (const float*)d_in[5];
    const float* Wo   = (const float*)d_in[6];
    const float* bo   = (const float*)d_in[7];

    float* out0 = (float*)d_out;                       // (128, 8192) logsoftmax
    float* out2 = out0 + (size_t)OUT_SZ * T_STEPS;     // (2048, 8192) rate_all

    u64* ring = (u64*)d_ws;                            // 3*HID u64 = 48 KB

    hipLaunchKernelGGL(k_init, dim3(8), dim3(256), 0, stream, rate, ring);
    hipLaunchKernelGGL(k_xproj, dim3(T_STEPS / 512, HID / 32), dim3(256), 0, stream,
                       sig, Wi, bi, out2);

    void* args[] = {(void*)&Wh, (void*)&bh, (void*)&rate,
                    (void*)&out2, (void*)&ring};
    hipLaunchCooperativeKernel((const void*)k_scan, dim3(NBLK), dim3(256),
                               args, 0, stream);

    hipLaunchKernelGGL(k_logits, dim3(T_STEPS / 128), dim3(512), 0, stream,
                       out2, Wo, bo, out0);
}

// Round 5
// 16595.404 us; speedup vs baseline: 15.3063x; 1.9824x over previous
//
#include <hip/hip_runtime.h>
#include <math.h>

#define T_STEPS 8192
#define HID     2048
#define IN_SZ   256
#define OUT_SZ  128
#define NBLK    128            // scan workgroups (1 per CU, 128 CUs used)
#define NTHR    512            // 8 waves
#define RPB     16             // rows per workgroup = HID/NBLK
#define SCRUB   0xFFFFFFFF00000000ull

typedef unsigned long long u64;
typedef unsigned int u32;
typedef __attribute__((ext_vector_type(4))) u32 u32x4;

// ---------------------------------------------------------------------------
// ws layout: u64 ring[3][HID]. Entry = (tag<<32) | float_bits; slot t%3 holds
// r_t tagged t. Producers: fire-and-forget 8B agent-scope atomic stores
// (PROVEN coherent, R3). Consumers: fast path polls 4 entries via two
// dwordx4 sc1 loads in one asm (1 round trip); every 8B half carries its own
// tag so wide reads are tear-proof. After 32 failed rounds, falls back to
// the proven __hip_atomic_load 8B path -> deadlock-impossible.
// Skew between blocks <=1 step => depth-3 ring never aliases (R3 argument).
// ---------------------------------------------------------------------------

__global__ void k_init(const float* __restrict__ rate, u64* ring) {
    int i = blockIdx.x * blockDim.x + threadIdx.x;
    if (i < HID) {
        ring[i] = (u64)__float_as_uint(rate[i]);   // tag 0 | r0 bits
        ring[HID + i]     = SCRUB;
        ring[2 * HID + i] = SCRUB;
    }
}

// ---------------------------------------------------------------------------
// xproj[h, t] = sum_i Wi[h,i] * sig[i,t] + bi[h]   -> written to out2 (H,T)
// ---------------------------------------------------------------------------
__global__ void __launch_bounds__(256) k_xproj(const float* __restrict__ sig,
                                               const float* __restrict__ Wi,
                                               const float* __restrict__ bi,
                                               float* __restrict__ out2) {
    __shared__ float wl[32 * IN_SZ];  // 32 KB
    const int tid = threadIdx.x;
    const int t0 = blockIdx.x * 512;
    const int h0 = blockIdx.y * 32;

    {
        const float4* s4 = (const float4*)(Wi + (size_t)h0 * IN_SZ);
        float4* d4 = (float4*)wl;
        #pragma unroll
        for (int k = 0; k < 8; ++k) d4[tid + k * 256] = s4[tid + k * 256];
    }
    __syncthreads();

    const int t1 = t0 + tid, t2 = t1 + 256;
    float acc1[32], acc2[32];
    #pragma unroll
    for (int j = 0; j < 32; ++j) { acc1[j] = 0.f; acc2[j] = 0.f; }

    for (int i = 0; i < IN_SZ; ++i) {
        float s1 = sig[(size_t)i * T_STEPS + t1];
        float s2 = sig[(size_t)i * T_STEPS + t2];
        #pragma unroll
        for (int j = 0; j < 32; ++j) {
            float w = wl[j * IN_SZ + i];
            acc1[j] = fmaf(w, s1, acc1[j]);
            acc2[j] = fmaf(w, s2, acc2[j]);
        }
    }
    #pragma unroll
    for (int j = 0; j < 32; ++j) {
        float b = bi[h0 + j];
        out2[(size_t)(h0 + j) * T_STEPS + t1] = acc1[j] + b;
        out2[(size_t)(h0 + j) * T_STEPS + t2] = acc2[j] + b;
    }
}

// ---------------------------------------------------------------------------
// Persistent scan. 128 blocks x 512 threads (cooperative). Block b owns rows
// h0 = b*16 .. +15; wave w (0..7) owns rows h0+2w, h0+2w+1; Wh in 128KB LDS.
// ---------------------------------------------------------------------------
__global__ void __launch_bounds__(512) k_scan(const float* __restrict__ Wh,
                                              const float* __restrict__ bh,
                                              float* __restrict__ out2,
                                              u64* ring) {
    __shared__ float whs[RPB * HID];  // 128 KB
    __shared__ float rl[HID];         // 8 KB
    const int tid  = threadIdx.x;
    const int bid  = blockIdx.x;
    const int w    = tid >> 6;
    const int lane = tid & 63;
    const int h0   = bid * RPB;
    const int ra   = h0 + 2 * w;
    const int rb   = ra + 1;

    {
        const float4* s4 = (const float4*)(Wh + (size_t)h0 * HID);
        float4* d4 = (float4*)whs;
        #pragma unroll
        for (int k = 0; k < RPB * HID / 4 / NTHR; ++k)
            d4[tid + k * NTHR] = s4[tid + k * NTHR];
    }
    const float bha = bh[ra], bhb = bh[rb];
    __syncthreads();

    int cur = 0;  // t % 3
    for (int t = 0; t < T_STEPS; ++t) {
        // ---- prefetch xp (hides under the poll) ----
        const size_t ia = (size_t)ra * T_STEPS + t;
        const size_t ib = (size_t)rb * T_STEPS + t;
        float xpa = 0.f, xpb = 0.f;
        if (lane == 0) { xpa = out2[ia]; xpb = out2[ib]; }

        // ---- acquire my 4 entries of slot cur (tag must == t) ----
        {
            const u64* src = ring + (size_t)cur * HID;
            const u64* p0p = src + 4 * tid;
            const u64* p1p = p0p + 2;
            const u32 tt = (u32)t;
            u32x4 a0, a1;
            float f0, f1, f2, f3;
            int got = 0;
            // fast path: two dwordx4 sc1 loads, one round trip
            for (int rounds = 0; rounds < 32; ++rounds) {
                asm volatile("global_load_dwordx4 %0, %2, off sc1\n\t"
                             "global_load_dwordx4 %1, %3, off sc1\n\t"
                             "s_waitcnt vmcnt(0)"
                             : "=&v"(a0), "=&v"(a1)
                             : "v"(p0p), "v"(p1p)
                             : "memory");
                __builtin_amdgcn_sched_barrier(0);
                if (a0.y == tt && a0.w == tt && a1.y == tt && a1.w == tt) {
                    f0 = __uint_as_float(a0.x);
                    f1 = __uint_as_float(a0.z);
                    f2 = __uint_as_float(a1.x);
                    f3 = __uint_as_float(a1.z);
                    got = 1;
                    break;
                }
            }
            if (!got) {
                // proven-coherent fallback (R3 path)
                u64 vals[4];
                unsigned pend = 0xFu;
                while (pend) {
                    #pragma unroll
                    for (int q = 0; q < 4; ++q) {
                        if (pend & (1u << q))
                            vals[q] = __hip_atomic_load(&p0p[q], __ATOMIC_RELAXED,
                                                        __HIP_MEMORY_SCOPE_AGENT);
                    }
                    #pragma unroll
                    for (int q = 0; q < 4; ++q) {
                        if ((pend & (1u << q)) && (u32)(vals[q] >> 32) == tt)
                            pend &= ~(1u << q);
                    }
                }
                f0 = __uint_as_float((u32)vals[0]);
                f1 = __uint_as_float((u32)vals[1]);
                f2 = __uint_as_float((u32)vals[2]);
                f3 = __uint_as_float((u32)vals[3]);
            }
            float4 v; v.x = f0; v.y = f1; v.z = f2; v.w = f3;
            ((float4*)rl)[tid] = v;   // ds_write_b128
        }
        __syncthreads();

        // ---- two dot products per wave (conflict-free b128 reads) ----
        float p0 = 0.f, p1 = 0.f;
        {
            const float4* r4 = (const float4*)rl;
            const float4* a4 = (const float4*)(whs + (size_t)(2 * w) * HID);
            const float4* b4 = (const float4*)(whs + (size_t)(2 * w + 1) * HID);
            #pragma unroll
            for (int c = 0; c < 8; ++c) {
                float4 rv = r4[c * 64 + lane];
                float4 av = a4[c * 64 + lane];
                float4 bv = b4[c * 64 + lane];
                p0 = fmaf(rv.x, av.x, p0); p0 = fmaf(rv.y, av.y, p0);
                p0 = fmaf(rv.z, av.z, p0); p0 = fmaf(rv.w, av.w, p0);
                p1 = fmaf(rv.x, bv.x, p1); p1 = fmaf(rv.y, bv.y, p1);
                p1 = fmaf(rv.z, bv.z, p1); p1 = fmaf(rv.w, bv.w, p1);
            }
        }
        #pragma unroll
        for (int off = 32; off >= 1; off >>= 1) {
            p0 += __shfl_xor(p0, off, 64);
            p1 += __shfl_xor(p1, off, 64);
        }

        const int nxt = (cur == 2) ? 0 : cur + 1;
        if (lane == 0) {
            float rolda = rl[ra];
            float roldb = rl[rb];
            float va = p0 + xpa + bha;
            float vb = p1 + xpb + bhb;
            float rna = 0.9f * rolda + 0.1f * tanhf(va);
            float rnb = 0.9f * roldb + 0.1f * tanhf(vb);
            out2[ia] = rna;                    // rate_all output (plain, cached)
            out2[ib] = rnb;
            u64* dst = ring + (size_t)nxt * HID;
            const u64 tagbits = (u64)(u32)(t + 1) << 32;
            __hip_atomic_store(&dst[ra], tagbits | __float_as_uint(rna),
                               __ATOMIC_RELAXED, __HIP_MEMORY_SCOPE_AGENT);
            __hip_atomic_store(&dst[rb], tagbits | __float_as_uint(rnb),
                               __ATOMIC_RELAXED, __HIP_MEMORY_SCOPE_AGENT);
        }
        cur = nxt;
    }
}

// ---------------------------------------------------------------------------
// logits[t,o] = sum_h rates[t,h]*Wo[o,h] + bo[o]; out0[o,t] = logsoftmax_o.
// ---------------------------------------------------------------------------
__global__ void __launch_bounds__(512) k_logits(const float* __restrict__ out2,
                                                const float* __restrict__ Wo,
                                                const float* __restrict__ bo,
                                                float* __restrict__ out0) {
    __shared__ float wos[128 * 128];  // 64 KB
    __shared__ float red[8 * 128];    // 4 KB
    __shared__ float fin[128];
    const int tid  = threadIdx.x;
    const int w    = tid >> 6;
    const int lane = tid & 63;
    const int t0   = blockIdx.x * 128;
    const int ob   = w * 16;

    float acc0[16], acc1[16];
    #pragma unroll
    for (int j = 0; j < 16; ++j) { acc0[j] = 0.f; acc1[j] = 0.f; }

    for (int hb = 0; hb < HID / 128; ++hb) {
        __syncthreads();
        {
            const float4* wo4 = (const float4*)Wo;
            float4* ws4 = (float4*)wos;
            #pragma unroll
            for (int k = 0; k < 8; ++k) {
                int g = tid + k * 512;
                int o = g >> 5;
                int c = g & 31;
                ws4[g] = wo4[(size_t)o * (HID / 4) + hb * 32 + c];
            }
        }
        __syncthreads();
        for (int hh = 0; hh < 128; ++hh) {
            int h = hb * 128 + hh;
            float rA = out2[(size_t)h * T_STEPS + t0 + lane];
            float rB = out2[(size_t)h * T_STEPS + t0 + 64 + lane];
            #pragma unroll
            for (int j = 0; j < 16; ++j) {
                float wv = wos[(ob + j) * 128 + hh];
                acc0[j] = fmaf(wv, rA, acc0[j]);
                acc1[j] = fmaf(wv, rB, acc1[j]);
            }
        }
    }
    #pragma unroll
    for (int j = 0; j < 16; ++j) {
        float b = bo[ob + j];
        acc0[j] += b; acc1[j] += b;
    }

    float m0 = acc0[0], m1 = acc1[0];
    #pragma unroll
    for (int j = 1; j < 16; ++j) { m0 = fmaxf(m0, acc0[j]); m1 = fmaxf(m1, acc1[j]); }
    red[w * 128 + lane] = m0;
    red[w * 128 + 64 + lane] = m1;
    __syncthreads();
    if (tid < 128) {
        float m = red[tid];
        #pragma unroll
        for (int q = 1; q < 8; ++q) m = fmaxf(m, red[q * 128 + tid]);
        fin[tid] = m;
    }
    __syncthreads();
    float fm0 = fin[lane], fm1 = fin[64 + lane];
    float s0 = 0.f, s1 = 0.f;
    #pragma unroll
    for (int j = 0; j < 16; ++j) {
        s0 += expf(acc0[j] - fm0);
        s1 += expf(acc1[j] - fm1);
    }
    red[w * 128 + lane] = s0;
    red[w * 128 + 64 + lane] = s1;
    __syncthreads();
    if (tid < 128) {
        float s = 0.f;
        #pragma unroll
        for (int q = 0; q < 8; ++q) s += red[q * 128 + tid];
        fin[tid] = fin[tid] + logf(s);
    }
    __syncthreads();
    float L0 = fin[lane], L1 = fin[64 + lane];
    #pragma unroll
    for (int j = 0; j < 16; ++j) {
        out0[(size_t)(ob + j) * T_STEPS + t0 + lane]      = acc0[j] - L0;
        out0[(size_t)(ob + j) * T_STEPS + t0 + 64 + lane] = acc1[j] - L1;
    }
}

// ---------------------------------------------------------------------------
extern "C" void kernel_launch(void* const* d_in, const int* in_sizes, int n_in,
                              void* d_out, int out_size, void* d_ws, size_t ws_size,
                              hipStream_t stream) {
    const float* sig  = (const float*)d_in[0];
    const float* rate = (const float*)d_in[1];
    const float* Wi   = (const float*)d_in[2];
    const float* bi   = (const float*)d_in[3];
    const float* Wh   = (const float*)d_in[4];
    const float* bh   = (const float*)d_in[5];
    const float* Wo   = (const float*)d_in[6];
    const float* bo   = (const float*)d_in[7];

    float* out0 = (float*)d_out;                       // (128, 8192) logsoftmax
    float* out2 = out0 + (size_t)OUT_SZ * T_STEPS;     // (2048, 8192) rate_all

    u64* ring = (u64*)d_ws;                            // 3*HID u64 = 48 KB

    hipLaunchKernelGGL(k_init, dim3(8), dim3(256), 0, stream, rate, ring);
    hipLaunchKernelGGL(k_xproj, dim3(T_STEPS / 512, HID / 32), dim3(256), 0, stream,
                       sig, Wi, bi, out2);

    void* args[] = {(void*)&Wh, (void*)&bh, (void*)&out2, (void*)&ring};
    hipLaunchCooperativeKernel((const void*)k_scan, dim3(NBLK), dim3(NTHR),
                               args, 0, stream);

    hipLaunchKernelGGL(k_logits, dim3(T_STEPS / 128), dim3(512), 0, stream,
                       out2, Wo, bo, out0);
}